// Round 1
// baseline (900.895 us; speedup 1.0000x reference)
//
#include <hip/hip_runtime.h>
#include <hip/hip_bf16.h>
#include <math.h>

// Problem constants
#define BN   4096
#define MN   64
#define DN   512
#define DOUTN 256
#define NHN  8

typedef __attribute__((ext_vector_type(8))) short s16x8;
typedef __attribute__((ext_vector_type(4))) float f32x4;

__device__ __forceinline__ unsigned short f2bf(float f) {
    unsigned int u = __float_as_uint(f);
    u += 0x7fffu + ((u >> 16) & 1u);           // RNE
    return (unsigned short)(u >> 16);
}
__device__ __forceinline__ float bf2f(unsigned short u) {
    return __uint_as_float(((unsigned int)u) << 16);
}

// ---------------- fp32 -> bf16 weight conversion (vectorized) ----------------
__global__ void k_conv_bf16(const float* __restrict__ src,
                            unsigned short* __restrict__ dst, int n4) {
    int i = blockIdx.x * blockDim.x + threadIdx.x;
    if (i < n4) {
        float4 v = ((const float4*)src)[i];
        ushort4 o;
        o.x = f2bf(v.x); o.y = f2bf(v.y); o.z = f2bf(v.z); o.w = f2bf(v.w);
        ((ushort4*)dst)[i] = o;
    }
}

// ---------------- q = agg_query @ Wq^T + bq  (512 outputs, wave per output) --
__global__ void k_q(const float* __restrict__ aq, const float* __restrict__ ipw,
                    const float* __restrict__ ipb, float* __restrict__ qv) {
    int wv = threadIdx.x >> 6, lane = threadIdx.x & 63;
    int i = blockIdx.x * 4 + wv;   // 128 blocks * 4 waves = 512 outputs
    const float* row = ipw + (size_t)i * 512 + lane * 8;
    const float* a = aq + lane * 8;
    float p = 0.f;
#pragma unroll
    for (int j = 0; j < 8; j++) p += a[j] * row[j];
#pragma unroll
    for (int off = 32; off >= 1; off >>= 1) p += __shfl_xor(p, off);
    if (lane == 0) qv[i] = p + ipb[i];
}

// ---------------- qk[h][d] = sum_j q[h*64+j] * Wk[h*64+j][d] -----------------
__global__ void k_qk(const float* __restrict__ qv, const float* __restrict__ ipw,
                     float* __restrict__ qk) {
    __shared__ float qs[64];
    int h = blockIdx.x, t = threadIdx.x;
    if (t < 64) qs[t] = qv[h * 64 + t];
    __syncthreads();
    float a0 = 0.f, a1 = 0.f;
    for (int j = 0; j < 64; j++) {
        const float* row = ipw + (size_t)(512 + h * 64 + j) * 512;
        float qj = qs[j];
        a0 += qj * row[t];
        a1 += qj * row[t + 256];
    }
    qk[h * 512 + t]       = a0;
    qk[h * 512 + t + 256] = a1;
}

// ---------------- main streaming kernel: scores/softmax/ph/zw ----------------
// One block per batch element. H[b] (64x512 f32, 128KB) staged once to LDS as
// bf16 (64KB -> 2 blocks/CU). Everything else reads LDS, H is read from HBM
// exactly once.
__global__ __launch_bounds__(256) void k_attn(
        const float* __restrict__ H, const float* __restrict__ w,
        const float* __restrict__ qk, unsigned short* __restrict__ ph,
        float* __restrict__ zw) {
    __shared__ unsigned short Hs[64 * 512];   // 64 KB, row-major [m][d]
    __shared__ float sc[8][64];               // scores [h][m]
    __shared__ float attn_t[64][8];           // attn transposed [m][h] for b128 broadcast reads
    __shared__ float wrow[64];
    const int t = threadIdx.x, lane = t & 63, wv = t >> 6;
    const int b = blockIdx.x;

    if (t < 64) wrow[t] = w[b * 64 + t];

    // Stage H[b] -> LDS bf16 (coalesced float4 loads)
    const float4* Hg = (const float4*)(H + (size_t)b * 32768);
#pragma unroll 8
    for (int c = 0; c < 32; c++) {
        int idx = c * 256 + t;
        float4 v = Hg[idx];
        ushort4 o;
        o.x = f2bf(v.x); o.y = f2bf(v.y); o.z = f2bf(v.z); o.w = f2bf(v.w);
        ((ushort4*)Hs)[idx] = o;
    }

    // qk into registers: lane owns d = lane*8 .. lane*8+7 (all heads)
    float qkr[8][8];
#pragma unroll
    for (int h = 0; h < 8; h++) {
        float4 v0 = *(const float4*)(qk + h * 512 + lane * 8);
        float4 v1 = *(const float4*)(qk + h * 512 + lane * 8 + 4);
        qkr[h][0] = v0.x; qkr[h][1] = v0.y; qkr[h][2] = v0.z; qkr[h][3] = v0.w;
        qkr[h][4] = v1.x; qkr[h][5] = v1.y; qkr[h][6] = v1.z; qkr[h][7] = v1.w;
    }
    __syncthreads();

    // Scores: wave wv handles rows m = wv*16 .. wv*16+15
    for (int mi = 0; mi < 16; mi++) {
        int m = wv * 16 + mi;
        const ushort4* hp = (const ushort4*)(Hs + m * 512 + lane * 8);
        ushort4 u0 = hp[0], u1 = hp[1];
        float hv[8] = { bf2f(u0.x), bf2f(u0.y), bf2f(u0.z), bf2f(u0.w),
                        bf2f(u1.x), bf2f(u1.y), bf2f(u1.z), bf2f(u1.w) };
        float p[8];
#pragma unroll
        for (int h = 0; h < 8; h++) {
            float s = 0.f;
#pragma unroll
            for (int j = 0; j < 8; j++) s += hv[j] * qkr[h][j];
            p[h] = s;
        }
#pragma unroll
        for (int off = 32; off >= 1; off >>= 1) {
#pragma unroll
            for (int h = 0; h < 8; h++) p[h] += __shfl_xor(p[h], off);
        }
        if (lane == 0) {
#pragma unroll
            for (int h = 0; h < 8; h++) sc[h][m] = p[h];
        }
    }
    __syncthreads();

    // Softmax: wave wv handles heads 2wv, 2wv+1; lane <-> m. bk is constant
    // over m -> dropped (softmax shift invariance). Scale = 1/sqrt(64) = 1/8.
#pragma unroll
    for (int hh = 0; hh < 2; hh++) {
        int h = wv * 2 + hh;
        float s = sc[h][lane] * 0.125f;
        float mx = s;
#pragma unroll
        for (int off = 32; off >= 1; off >>= 1) mx = fmaxf(mx, __shfl_xor(mx, off));
        float e = expf(s - mx);
        float sum = e;
#pragma unroll
        for (int off = 32; off >= 1; off >>= 1) sum += __shfl_xor(sum, off);
        attn_t[lane][h] = e / sum;
    }
    __syncthreads();

    // ph[h][d] = sum_m attn[h][m]*H[m][d] ; zw[d] = sum_m w[m]*H[m][d]
    // Thread owns cols d0, d0+1. attn_t[m][0..7] read as two b128 broadcasts.
    float pa0[8], pa1[8], za0 = 0.f, za1 = 0.f;
#pragma unroll
    for (int h = 0; h < 8; h++) { pa0[h] = 0.f; pa1[h] = 0.f; }
    const int d0 = t * 2;
    for (int m = 0; m < 64; m++) {
        float4 a03 = *(const float4*)&attn_t[m][0];
        float4 a47 = *(const float4*)&attn_t[m][4];
        ushort2 hu = *(const ushort2*)(Hs + m * 512 + d0);
        float h0 = bf2f(hu.x), h1 = bf2f(hu.y);
        float wm = wrow[m];
        za0 += wm * h0; za1 += wm * h1;
        pa0[0] += a03.x * h0; pa1[0] += a03.x * h1;
        pa0[1] += a03.y * h0; pa1[1] += a03.y * h1;
        pa0[2] += a03.z * h0; pa1[2] += a03.z * h1;
        pa0[3] += a03.w * h0; pa1[3] += a03.w * h1;
        pa0[4] += a47.x * h0; pa1[4] += a47.x * h1;
        pa0[5] += a47.y * h0; pa1[5] += a47.y * h1;
        pa0[6] += a47.z * h0; pa1[6] += a47.z * h1;
        pa0[7] += a47.w * h0; pa1[7] += a47.w * h1;
    }
    float2 zz; zz.x = za0; zz.y = za1;
    *(float2*)(zw + (size_t)b * 512 + d0) = zz;
#pragma unroll
    for (int h = 0; h < 8; h++) {
        ushort2 o; o.x = f2bf(pa0[h]); o.y = f2bf(pa1[h]);
        *(ushort2*)(ph + (size_t)b * 4096 + h * 512 + d0) = o;
    }
}

// ---------------- bf16 MFMA GEMM core: 64x64 tile, K=512, no LDS -------------
// out[b][n] = sum_k A[b][k] * W[n][k]. Wave wv computes 64 rows x 16 cols
// (n-subtile wv*16). a_frag: A[m=lane&15][k=quad*8+j]; b_frag: W[n=lane&15][k].
// D: row = quad*4 + reg, col = lane&15.  (verified gfx950 layouts)
__device__ __forceinline__ void gemm_acc(const unsigned short* __restrict__ A,
                                         int aStride,
                                         const unsigned short* __restrict__ Wt,
                                         f32x4 acc[4]) {
    const int lane = threadIdx.x & 63;
    const int wv = threadIdx.x >> 6;
    const int mh = lane & 15, q = lane >> 4;
    const unsigned short* aP = A + (size_t)mh * aStride + q * 8;
    const unsigned short* bP = Wt + (size_t)(wv * 16 + mh) * 512 + q * 8;
#pragma unroll 4
    for (int kk = 0; kk < 512; kk += 32) {
        s16x8 bb = *(const s16x8*)(bP + kk);
#pragma unroll
        for (int tt = 0; tt < 4; tt++) {
            s16x8 aa = *(const s16x8*)(aP + (size_t)tt * 16 * aStride + kk);
            acc[tt] = __builtin_amdgcn_mfma_f32_16x16x32_bf16(aa, bb, acc[tt], 0, 0, 0);
        }
    }
}

// C1: ctx[b][h*64+j] = sum_d ph[b][h][d] * Wv[h*64+j][d] + bv   -> bf16
__global__ __launch_bounds__(256) void k_ctx(
        const unsigned short* __restrict__ ph, const unsigned short* __restrict__ Wv16,
        const float* __restrict__ ipb, unsigned short* __restrict__ ctx16) {
    const int h = blockIdx.x;           // col tile == head
    const int b0 = blockIdx.y * 64;
    f32x4 acc[4];
#pragma unroll
    for (int i = 0; i < 4; i++) { acc[i][0]=0.f; acc[i][1]=0.f; acc[i][2]=0.f; acc[i][3]=0.f; }
    gemm_acc(ph + (size_t)b0 * 4096 + h * 512, 4096,
             Wv16 + (size_t)(h * 64) * 512, acc);
    const int lane = threadIdx.x & 63, wv = threadIdx.x >> 6;
    const int mh = lane & 15, q = lane >> 4;
    const int col = h * 64 + wv * 16 + mh;
    const float bv = ipb[1024 + col];
#pragma unroll
    for (int tt = 0; tt < 4; tt++) {
#pragma unroll
        for (int r = 0; r < 4; r++) {
            int row = b0 + tt * 16 + q * 4 + r;
            ctx16[(size_t)row * 512 + col] = f2bf(acc[tt][r] + bv);
        }
    }
}

// C2: z[b][n] = zw[b][n] + sum_k ctx[b][k]*Wo[n][k] + bo[n]   -> f32
__global__ __launch_bounds__(256) void k_zproj(
        const unsigned short* __restrict__ ctx16, const unsigned short* __restrict__ Wo16,
        const float* __restrict__ zw, const float* __restrict__ opb,
        float* __restrict__ z) {
    const int n0 = blockIdx.x * 64, b0 = blockIdx.y * 64;
    f32x4 acc[4];
#pragma unroll
    for (int i = 0; i < 4; i++) { acc[i][0]=0.f; acc[i][1]=0.f; acc[i][2]=0.f; acc[i][3]=0.f; }
    gemm_acc(ctx16 + (size_t)b0 * 512, 512, Wo16 + (size_t)n0 * 512, acc);
    const int lane = threadIdx.x & 63, wv = threadIdx.x >> 6;
    const int mh = lane & 15, q = lane >> 4;
    const int col = n0 + wv * 16 + mh;
    const float bo = opb[col];
#pragma unroll
    for (int tt = 0; tt < 4; tt++) {
#pragma unroll
        for (int r = 0; r < 4; r++) {
            int row = b0 + tt * 16 + q * 4 + r;
            z[(size_t)row * 512 + col] = acc[tt][r] + zw[(size_t)row * 512 + col] + bo;
        }
    }
}

// LayerNorm: zn = (z - mu)/sqrt(var+eps)*g + b  -> bf16. Wave per row.
__global__ __launch_bounds__(256) void k_ln(
        const float* __restrict__ z, const float* __restrict__ g,
        const float* __restrict__ bta, unsigned short* __restrict__ zn16) {
    const int wv = threadIdx.x >> 6, lane = threadIdx.x & 63;
    const int row = blockIdx.x * 4 + wv;
    const float* zr = z + (size_t)row * 512 + lane * 8;
    float4 v0 = *(const float4*)zr;
    float4 v1 = *(const float4*)(zr + 4);
    float x[8] = { v0.x, v0.y, v0.z, v0.w, v1.x, v1.y, v1.z, v1.w };
    float s1 = 0.f, s2 = 0.f;
#pragma unroll
    for (int j = 0; j < 8; j++) { s1 += x[j]; s2 += x[j] * x[j]; }
#pragma unroll
    for (int off = 32; off >= 1; off >>= 1) {
        s1 += __shfl_xor(s1, off);
        s2 += __shfl_xor(s2, off);
    }
    float mean = s1 * (1.f / 512.f);
    float var = s2 * (1.f / 512.f) - mean * mean;
    float inv = rsqrtf(fmaxf(var, 0.f) + 1e-5f);
    float4 g0 = *(const float4*)(g + lane * 8);
    float4 g1 = *(const float4*)(g + lane * 8 + 4);
    float4 b0 = *(const float4*)(bta + lane * 8);
    float4 b1 = *(const float4*)(bta + lane * 8 + 4);
    float gg[8] = { g0.x, g0.y, g0.z, g0.w, g1.x, g1.y, g1.z, g1.w };
    float bb[8] = { b0.x, b0.y, b0.z, b0.w, b1.x, b1.y, b1.z, b1.w };
    ushort4 o0, o1;
    o0.x = f2bf((x[0]-mean)*inv*gg[0]+bb[0]);
    o0.y = f2bf((x[1]-mean)*inv*gg[1]+bb[1]);
    o0.z = f2bf((x[2]-mean)*inv*gg[2]+bb[2]);
    o0.w = f2bf((x[3]-mean)*inv*gg[3]+bb[3]);
    o1.x = f2bf((x[4]-mean)*inv*gg[4]+bb[4]);
    o1.y = f2bf((x[5]-mean)*inv*gg[5]+bb[5]);
    o1.z = f2bf((x[6]-mean)*inv*gg[6]+bb[6]);
    o1.w = f2bf((x[7]-mean)*inv*gg[7]+bb[7]);
    ushort4* op = (ushort4*)(zn16 + (size_t)row * 512 + lane * 8);
    op[0] = o0; op[1] = o1;
}

// C3: h1 = gelu_exact(zn @ w1^T + b1) -> bf16
__global__ __launch_bounds__(256) void k_mlp1(
        const unsigned short* __restrict__ zn16, const unsigned short* __restrict__ w116,
        const float* __restrict__ b1, unsigned short* __restrict__ h116) {
    const int n0 = blockIdx.x * 64, b0 = blockIdx.y * 64;
    f32x4 acc[4];
#pragma unroll
    for (int i = 0; i < 4; i++) { acc[i][0]=0.f; acc[i][1]=0.f; acc[i][2]=0.f; acc[i][3]=0.f; }
    gemm_acc(zn16 + (size_t)b0 * 512, 512, w116 + (size_t)n0 * 512, acc);
    const int lane = threadIdx.x & 63, wv = threadIdx.x >> 6;
    const int mh = lane & 15, q = lane >> 4;
    const int col = n0 + wv * 16 + mh;
    const float bias = b1[col];
#pragma unroll
    for (int tt = 0; tt < 4; tt++) {
#pragma unroll
        for (int r = 0; r < 4; r++) {
            int row = b0 + tt * 16 + q * 4 + r;
            float v = acc[tt][r] + bias;
            float gl = 0.5f * v * (1.0f + erff(v * 0.70710678118654752f));
            h116[(size_t)row * 512 + col] = f2bf(gl);
        }
    }
}

// C4: out = h1 @ w2^T + b2, nan_to_num -> f32 d_out
__global__ __launch_bounds__(256) void k_mlp2(
        const unsigned short* __restrict__ h116, const unsigned short* __restrict__ w216,
        const float* __restrict__ b2, float* __restrict__ out) {
    const int n0 = blockIdx.x * 64, b0 = blockIdx.y * 64;
    f32x4 acc[4];
#pragma unroll
    for (int i = 0; i < 4; i++) { acc[i][0]=0.f; acc[i][1]=0.f; acc[i][2]=0.f; acc[i][3]=0.f; }
    gemm_acc(h116 + (size_t)b0 * 512, 512, w216 + (size_t)n0 * 512, acc);
    const int lane = threadIdx.x & 63, wv = threadIdx.x >> 6;
    const int mh = lane & 15, q = lane >> 4;
    const int col = n0 + wv * 16 + mh;
    const float bias = b2[col];
#pragma unroll
    for (int tt = 0; tt < 4; tt++) {
#pragma unroll
        for (int r = 0; r < 4; r++) {
            int row = b0 + tt * 16 + q * 4 + r;
            float v = acc[tt][r] + bias;
            if (isnan(v)) v = 0.f;
            else if (isinf(v)) v = v > 0.f ? 3.402823466e38f : -3.402823466e38f;
            out[(size_t)row * 256 + col] = v;
        }
    }
}

// ---------------- workspace layout (bytes) ----------------
#define WS_Q     0u           //   512 f32
#define WS_QK    4096u        //  8*512 f32
#define WS_WV16  20480u       // 262144 bf16
#define WS_WO16  544768u
#define WS_W116  1069056u
#define WS_W216  1593344u     // 131072 bf16
#define WS_PH    2097152u     // 4096*4096 bf16 (32 MB)
#define WS_ZW    35651584u    // 4096*512 f32 (8 MB)
#define WS_CTX16 44040192u    // 4096*512 bf16 (4 MB)
#define WS_Z     48234496u    // 4096*512 f32 (8 MB)
#define WS_ZN16  56623104u    // 4 MB
#define WS_H116  60817408u    // 4 MB  -> total ~62 MB

extern "C" void kernel_launch(void* const* d_in, const int* in_sizes, int n_in,
                              void* d_out, int out_size, void* d_ws, size_t ws_size,
                              hipStream_t stream) {
    const float* H   = (const float*)d_in[0];
    const float* w   = (const float*)d_in[1];
    const float* aq  = (const float*)d_in[2];
    const float* ipw = (const float*)d_in[3];
    const float* ipb = (const float*)d_in[4];
    const float* opw = (const float*)d_in[5];
    const float* opb = (const float*)d_in[6];
    const float* lng = (const float*)d_in[7];
    const float* lnb = (const float*)d_in[8];
    const float* w1  = (const float*)d_in[9];
    const float* b1  = (const float*)d_in[10];
    const float* w2  = (const float*)d_in[11];
    const float* b2  = (const float*)d_in[12];
    float* out = (float*)d_out;
    char* ws = (char*)d_ws;

    float* qv            = (float*)(ws + WS_Q);
    float* qk            = (float*)(ws + WS_QK);
    unsigned short* Wv16 = (unsigned short*)(ws + WS_WV16);
    unsigned short* Wo16 = (unsigned short*)(ws + WS_WO16);
    unsigned short* w116 = (unsigned short*)(ws + WS_W116);
    unsigned short* w216 = (unsigned short*)(ws + WS_W216);
    unsigned short* ph   = (unsigned short*)(ws + WS_PH);
    float* zw            = (float*)(ws + WS_ZW);
    unsigned short* ctx16= (unsigned short*)(ws + WS_CTX16);
    float* z             = (float*)(ws + WS_Z);
    unsigned short* zn16 = (unsigned short*)(ws + WS_ZN16);
    unsigned short* h116 = (unsigned short*)(ws + WS_H116);

    // Weight conversions (Wv = in_proj_w rows 1024..1535)
    k_conv_bf16<<<256, 256, 0, stream>>>(ipw + (size_t)1024 * 512, Wv16, 65536);
    k_conv_bf16<<<256, 256, 0, stream>>>(opw, Wo16, 65536);
    k_conv_bf16<<<256, 256, 0, stream>>>(w1, w116, 65536);
    k_conv_bf16<<<128, 256, 0, stream>>>(w2, w216, 32768);

    // q, qk precompute
    k_q<<<128, 256, 0, stream>>>(aq, ipw, ipb, qv);
    k_qk<<<8, 256, 0, stream>>>(qv, ipw, qk);

    // Main streaming pass over H
    k_attn<<<4096, 256, 0, stream>>>(H, w, qk, ph, zw);

    // Epilogue GEMM chain (bf16 MFMA)
    k_ctx  <<<dim3(8, 64), 256, 0, stream>>>(ph, Wv16, ipb, ctx16);
    k_zproj<<<dim3(8, 64), 256, 0, stream>>>(ctx16, Wo16, zw, opb, z);
    k_ln   <<<1024, 256, 0, stream>>>(z, lng, lnb, zn16);
    k_mlp1 <<<dim3(8, 64), 256, 0, stream>>>(zn16, w116, b1, h116);
    k_mlp2 <<<dim3(4, 64), 256, 0, stream>>>(h116, w216, b2, out);
}

// Round 2
// 806.563 us; speedup vs baseline: 1.1170x; 1.1170x over previous
//
#include <hip/hip_runtime.h>
#include <hip/hip_bf16.h>
#include <math.h>

// Problem constants
#define BN   4096
#define MN   64
#define DN   512
#define DOUTN 256
#define NHN  8

typedef __attribute__((ext_vector_type(8))) short s16x8;
typedef __attribute__((ext_vector_type(4))) float f32x4;

__device__ __forceinline__ unsigned short f2bf(float f) {
    unsigned int u = __float_as_uint(f);
    u += 0x7fffu + ((u >> 16) & 1u);           // RNE
    return (unsigned short)(u >> 16);
}
__device__ __forceinline__ float bf2f(unsigned short u) {
    return __uint_as_float(((unsigned int)u) << 16);
}

// ------------- fused fp32 -> bf16 weight conversion (4 regions, 1 launch) ----
__global__ void k_conv_all(const float* __restrict__ s0, const float* __restrict__ s1,
                           const float* __restrict__ s2, const float* __restrict__ s3,
                           unsigned short* __restrict__ d0, unsigned short* __restrict__ d1,
                           unsigned short* __restrict__ d2, unsigned short* __restrict__ d3) {
    int i = blockIdx.x * blockDim.x + threadIdx.x;   // float4 index, total 229376
    const float* s; unsigned short* d; int off;
    if (i < 65536)       { s = s0; d = d0; off = i; }
    else if (i < 131072) { s = s1; d = d1; off = i - 65536; }
    else if (i < 196608) { s = s2; d = d2; off = i - 131072; }
    else                 { s = s3; d = d3; off = i - 196608; }
    float4 v = ((const float4*)s)[off];
    ushort4 o;
    o.x = f2bf(v.x); o.y = f2bf(v.y); o.z = f2bf(v.z); o.w = f2bf(v.w);
    ((ushort4*)d)[off] = o;
}

// ---------------- q = agg_query @ Wq^T + bq  (512 outputs, wave per output) --
__global__ void k_q(const float* __restrict__ aq, const float* __restrict__ ipw,
                    const float* __restrict__ ipb, float* __restrict__ qv) {
    int wv = threadIdx.x >> 6, lane = threadIdx.x & 63;
    int i = blockIdx.x * 4 + wv;   // 128 blocks * 4 waves = 512 outputs
    const float* row = ipw + (size_t)i * 512 + lane * 8;
    const float* a = aq + lane * 8;
    float p = 0.f;
#pragma unroll
    for (int j = 0; j < 8; j++) p += a[j] * row[j];
#pragma unroll
    for (int off = 32; off >= 1; off >>= 1) p += __shfl_xor(p, off);
    if (lane == 0) qv[i] = p + ipb[i];
}

// ------- qkb16[h][d] = bf16( 0.125 * sum_j q[h*64+j] * Wk[h*64+j][d] ) -------
// 16 rows: h=0..7 real, h=8..15 zero (MFMA B-operand padding).
__global__ void k_qk(const float* __restrict__ qv, const float* __restrict__ ipw,
                     unsigned short* __restrict__ qkb) {
    int h = blockIdx.x, t = threadIdx.x;
    if (h >= 8) {
        qkb[h * 512 + t] = 0;
        qkb[h * 512 + t + 256] = 0;
        return;
    }
    __shared__ float qs[64];
    if (t < 64) qs[t] = qv[h * 64 + t];
    __syncthreads();
    float a0 = 0.f, a1 = 0.f;
    for (int j = 0; j < 64; j++) {
        const float* row = ipw + (size_t)(512 + h * 64 + j) * 512;
        float qj = qs[j];
        a0 += qj * row[t];
        a1 += qj * row[t + 256];
    }
    qkb[h * 512 + t]       = f2bf(a0 * 0.125f);
    qkb[h * 512 + t + 256] = f2bf(a1 * 0.125f);
}

// ---------------- main streaming kernel: scores/softmax/ph/zw ----------------
// One block per batch element. H[b] (64x512 f32) staged once to LDS as bf16
// with rows padded to 520 elements (1040B stride -> 2-way bank alias = free
// for the MFMA b128 fragment reads). Scores computed by MFMA (16 MFMAs/wave
// replaces the old ~2700-inst shuffle-reduce phase). H read from HBM once.
__global__ __launch_bounds__(256) void k_attn(
        const float* __restrict__ H, const float* __restrict__ w,
        const unsigned short* __restrict__ qkb, unsigned short* __restrict__ ph,
        float* __restrict__ zw) {
    __shared__ unsigned short Hs[64 * 520];   // 66.6 KB, padded row stride
    __shared__ float sc[8][64];               // scores [h][m]
    __shared__ float attn_t[64][8];           // attn transposed [m][h]
    __shared__ float wrow[64];
    const int t = threadIdx.x, lane = t & 63, wv = t >> 6;
    const int mh = lane & 15, q = lane >> 4;
    const int b = blockIdx.x;

    if (t < 64) wrow[t] = w[b * 64 + t];

    // Stage H[b] -> LDS bf16 (coalesced float4 loads; padded-row writes)
    const float4* Hg = (const float4*)(H + (size_t)b * 32768);
#pragma unroll 8
    for (int c = 0; c < 32; c++) {
        int idx = c * 256 + t;
        int m = idx >> 7, dc = (idx & 127) * 4;
        float4 v = Hg[idx];
        ushort4 o;
        o.x = f2bf(v.x); o.y = f2bf(v.y); o.z = f2bf(v.z); o.w = f2bf(v.w);
        *(ushort4*)(Hs + m * 520 + dc) = o;
    }
    __syncthreads();

    // Scores via MFMA: wave wv owns m-tile rows wv*16..wv*16+15.
    // D[m][h] = sum_d Hs[m][d] * qkb[h][d]  (scale already folded into qkb).
    {
        const unsigned short* aP = Hs + (wv * 16 + mh) * 520 + q * 8;
        const unsigned short* bP = qkb + mh * 512 + q * 8;
        f32x4 acc = {0.f, 0.f, 0.f, 0.f};
#pragma unroll
        for (int kk = 0; kk < 512; kk += 32) {
            s16x8 aa = *(const s16x8*)(aP + kk);
            s16x8 bb = *(const s16x8*)(bP + kk);
            acc = __builtin_amdgcn_mfma_f32_16x16x32_bf16(aa, bb, acc, 0, 0, 0);
        }
        if (mh < 8) {
#pragma unroll
            for (int r = 0; r < 4; r++) sc[mh][wv * 16 + q * 4 + r] = acc[r];
        }
    }
    __syncthreads();

    // Softmax: wave wv handles heads 2wv, 2wv+1; lane <-> m. bk constant over
    // m -> dropped (shift invariance).
#pragma unroll
    for (int hh = 0; hh < 2; hh++) {
        int h = wv * 2 + hh;
        float s = sc[h][lane];
        float mx = s;
#pragma unroll
        for (int off = 32; off >= 1; off >>= 1) mx = fmaxf(mx, __shfl_xor(mx, off));
        float e = expf(s - mx);
        float sum = e;
#pragma unroll
        for (int off = 32; off >= 1; off >>= 1) sum += __shfl_xor(sum, off);
        attn_t[lane][h] = e / sum;
    }
    __syncthreads();

    // ph[h][d] = sum_m attn[h][m]*H[m][d] ; zw[d] = sum_m w[m]*H[m][d]
    // Thread owns cols d0, d0+1. attn_t[m][0..7] read as two b128 broadcasts.
    float pa0[8], pa1[8], za0 = 0.f, za1 = 0.f;
#pragma unroll
    for (int h = 0; h < 8; h++) { pa0[h] = 0.f; pa1[h] = 0.f; }
    const int d0 = t * 2;
    for (int m = 0; m < 64; m++) {
        float4 a03 = *(const float4*)&attn_t[m][0];
        float4 a47 = *(const float4*)&attn_t[m][4];
        ushort2 hu = *(const ushort2*)(Hs + m * 520 + d0);
        float h0 = bf2f(hu.x), h1 = bf2f(hu.y);
        float wm = wrow[m];
        za0 += wm * h0; za1 += wm * h1;
        pa0[0] += a03.x * h0; pa1[0] += a03.x * h1;
        pa0[1] += a03.y * h0; pa1[1] += a03.y * h1;
        pa0[2] += a03.z * h0; pa1[2] += a03.z * h1;
        pa0[3] += a03.w * h0; pa1[3] += a03.w * h1;
        pa0[4] += a47.x * h0; pa1[4] += a47.x * h1;
        pa0[5] += a47.y * h0; pa1[5] += a47.y * h1;
        pa0[6] += a47.z * h0; pa1[6] += a47.z * h1;
        pa0[7] += a47.w * h0; pa1[7] += a47.w * h1;
    }
    float2 zz; zz.x = za0; zz.y = za1;
    *(float2*)(zw + (size_t)b * 512 + d0) = zz;
    // ph layout: [h][b][d] so the downstream GEMM gets stride-512 fragments
#pragma unroll
    for (int h = 0; h < 8; h++) {
        ushort2 o; o.x = f2bf(pa0[h]); o.y = f2bf(pa1[h]);
        *(ushort2*)(ph + (size_t)h * 2097152 + (size_t)b * 512 + d0) = o;
    }
}

// ---------------- bf16 MFMA GEMM core: 64x64 tile, K=512, no LDS -------------
// out[b][n] = sum_k A[b][k] * W[n][k]. Wave wv computes 64 rows x 16 cols
// (n-subtile wv*16). a_frag: A[m=lane&15][k=quad*8+j]; b_frag: W[n=lane&15][k].
// D: row = quad*4 + reg, col = lane&15.  (verified gfx950 layouts)
__device__ __forceinline__ void gemm_acc(const unsigned short* __restrict__ A,
                                         int aStride,
                                         const unsigned short* __restrict__ Wt,
                                         f32x4 acc[4]) {
    const int lane = threadIdx.x & 63;
    const int wv = threadIdx.x >> 6;
    const int mh = lane & 15, q = lane >> 4;
    const unsigned short* aP = A + (size_t)mh * aStride + q * 8;
    const unsigned short* bP = Wt + (size_t)(wv * 16 + mh) * 512 + q * 8;
#pragma unroll 4
    for (int kk = 0; kk < 512; kk += 32) {
        s16x8 bb = *(const s16x8*)(bP + kk);
#pragma unroll
        for (int tt = 0; tt < 4; tt++) {
            s16x8 aa = *(const s16x8*)(aP + (size_t)tt * 16 * aStride + kk);
            acc[tt] = __builtin_amdgcn_mfma_f32_16x16x32_bf16(aa, bb, acc[tt], 0, 0, 0);
        }
    }
}

// C1: ctx[b][h*64+j] = sum_d ph[h][b][d] * Wv[h*64+j][d] + bv   -> bf16
__global__ __launch_bounds__(256) void k_ctx(
        const unsigned short* __restrict__ ph, const unsigned short* __restrict__ Wv16,
        const float* __restrict__ ipb, unsigned short* __restrict__ ctx16) {
    const int h = blockIdx.x;           // col tile == head
    const int b0 = blockIdx.y * 64;
    f32x4 acc[4];
#pragma unroll
    for (int i = 0; i < 4; i++) { acc[i][0]=0.f; acc[i][1]=0.f; acc[i][2]=0.f; acc[i][3]=0.f; }
    gemm_acc(ph + (size_t)h * 2097152 + (size_t)b0 * 512, 512,
             Wv16 + (size_t)(h * 64) * 512, acc);
    const int lane = threadIdx.x & 63, wv = threadIdx.x >> 6;
    const int mh = lane & 15, q = lane >> 4;
    const int col = h * 64 + wv * 16 + mh;
    const float bv = ipb[1024 + col];
#pragma unroll
    for (int tt = 0; tt < 4; tt++) {
#pragma unroll
        for (int r = 0; r < 4; r++) {
            int row = b0 + tt * 16 + q * 4 + r;
            ctx16[(size_t)row * 512 + col] = f2bf(acc[tt][r] + bv);
        }
    }
}

// C2: z[b][n] = zw[b][n] + sum_k ctx[b][k]*Wo[n][k] + bo[n]   -> f32
__global__ __launch_bounds__(256) void k_zproj(
        const unsigned short* __restrict__ ctx16, const unsigned short* __restrict__ Wo16,
        const float* __restrict__ zw, const float* __restrict__ opb,
        float* __restrict__ z) {
    const int n0 = blockIdx.x * 64, b0 = blockIdx.y * 64;
    f32x4 acc[4];
#pragma unroll
    for (int i = 0; i < 4; i++) { acc[i][0]=0.f; acc[i][1]=0.f; acc[i][2]=0.f; acc[i][3]=0.f; }
    gemm_acc(ctx16 + (size_t)b0 * 512, 512, Wo16 + (size_t)n0 * 512, acc);
    const int lane = threadIdx.x & 63, wv = threadIdx.x >> 6;
    const int mh = lane & 15, q = lane >> 4;
    const int col = n0 + wv * 16 + mh;
    const float bo = opb[col];
#pragma unroll
    for (int tt = 0; tt < 4; tt++) {
#pragma unroll
        for (int r = 0; r < 4; r++) {
            int row = b0 + tt * 16 + q * 4 + r;
            z[(size_t)row * 512 + col] = acc[tt][r] + zw[(size_t)row * 512 + col] + bo;
        }
    }
}

// LayerNorm: zn = (z - mu)/sqrt(var+eps)*g + b  -> bf16. Wave per row.
__global__ __launch_bounds__(256) void k_ln(
        const float* __restrict__ z, const float* __restrict__ g,
        const float* __restrict__ bta, unsigned short* __restrict__ zn16) {
    const int wv = threadIdx.x >> 6, lane = threadIdx.x & 63;
    const int row = blockIdx.x * 4 + wv;
    const float* zr = z + (size_t)row * 512 + lane * 8;
    float4 v0 = *(const float4*)zr;
    float4 v1 = *(const float4*)(zr + 4);
    float x[8] = { v0.x, v0.y, v0.z, v0.w, v1.x, v1.y, v1.z, v1.w };
    float s1 = 0.f, s2 = 0.f;
#pragma unroll
    for (int j = 0; j < 8; j++) { s1 += x[j]; s2 += x[j] * x[j]; }
#pragma unroll
    for (int off = 32; off >= 1; off >>= 1) {
        s1 += __shfl_xor(s1, off);
        s2 += __shfl_xor(s2, off);
    }
    float mean = s1 * (1.f / 512.f);
    float var = s2 * (1.f / 512.f) - mean * mean;
    float inv = rsqrtf(fmaxf(var, 0.f) + 1e-5f);
    float4 g0 = *(const float4*)(g + lane * 8);
    float4 g1 = *(const float4*)(g + lane * 8 + 4);
    float4 b0 = *(const float4*)(bta + lane * 8);
    float4 b1 = *(const float4*)(bta + lane * 8 + 4);
    float gg[8] = { g0.x, g0.y, g0.z, g0.w, g1.x, g1.y, g1.z, g1.w };
    float bb[8] = { b0.x, b0.y, b0.z, b0.w, b1.x, b1.y, b1.z, b1.w };
    ushort4 o0, o1;
    o0.x = f2bf((x[0]-mean)*inv*gg[0]+bb[0]);
    o0.y = f2bf((x[1]-mean)*inv*gg[1]+bb[1]);
    o0.z = f2bf((x[2]-mean)*inv*gg[2]+bb[2]);
    o0.w = f2bf((x[3]-mean)*inv*gg[3]+bb[3]);
    o1.x = f2bf((x[4]-mean)*inv*gg[4]+bb[4]);
    o1.y = f2bf((x[5]-mean)*inv*gg[5]+bb[5]);
    o1.z = f2bf((x[6]-mean)*inv*gg[6]+bb[6]);
    o1.w = f2bf((x[7]-mean)*inv*gg[7]+bb[7]);
    ushort4* op = (ushort4*)(zn16 + (size_t)row * 512 + lane * 8);
    op[0] = o0; op[1] = o1;
}

// C3: h1 = gelu_exact(zn @ w1^T + b1) -> bf16
__global__ __launch_bounds__(256) void k_mlp1(
        const unsigned short* __restrict__ zn16, const unsigned short* __restrict__ w116,
        const float* __restrict__ b1, unsigned short* __restrict__ h116) {
    const int n0 = blockIdx.x * 64, b0 = blockIdx.y * 64;
    f32x4 acc[4];
#pragma unroll
    for (int i = 0; i < 4; i++) { acc[i][0]=0.f; acc[i][1]=0.f; acc[i][2]=0.f; acc[i][3]=0.f; }
    gemm_acc(zn16 + (size_t)b0 * 512, 512, w116 + (size_t)n0 * 512, acc);
    const int lane = threadIdx.x & 63, wv = threadIdx.x >> 6;
    const int mh = lane & 15, q = lane >> 4;
    const int col = n0 + wv * 16 + mh;
    const float bias = b1[col];
#pragma unroll
    for (int tt = 0; tt < 4; tt++) {
#pragma unroll
        for (int r = 0; r < 4; r++) {
            int row = b0 + tt * 16 + q * 4 + r;
            float v = acc[tt][r] + bias;
            float gl = 0.5f * v * (1.0f + erff(v * 0.70710678118654752f));
            h116[(size_t)row * 512 + col] = f2bf(gl);
        }
    }
}

// C4: out = h1 @ w2^T + b2, nan_to_num -> f32 d_out
__global__ __launch_bounds__(256) void k_mlp2(
        const unsigned short* __restrict__ h116, const unsigned short* __restrict__ w216,
        const float* __restrict__ b2, float* __restrict__ out) {
    const int n0 = blockIdx.x * 64, b0 = blockIdx.y * 64;
    f32x4 acc[4];
#pragma unroll
    for (int i = 0; i < 4; i++) { acc[i][0]=0.f; acc[i][1]=0.f; acc[i][2]=0.f; acc[i][3]=0.f; }
    gemm_acc(h116 + (size_t)b0 * 512, 512, w216 + (size_t)n0 * 512, acc);
    const int lane = threadIdx.x & 63, wv = threadIdx.x >> 6;
    const int mh = lane & 15, q = lane >> 4;
    const int col = n0 + wv * 16 + mh;
    const float bias = b2[col];
#pragma unroll
    for (int tt = 0; tt < 4; tt++) {
#pragma unroll
        for (int r = 0; r < 4; r++) {
            int row = b0 + tt * 16 + q * 4 + r;
            float v = acc[tt][r] + bias;
            if (isnan(v)) v = 0.f;
            else if (isinf(v)) v = v > 0.f ? 3.402823466e38f : -3.402823466e38f;
            out[(size_t)row * 256 + col] = v;
        }
    }
}

// ---------------- workspace layout (bytes) ----------------
#define WS_Q     0u           //   512 f32
#define WS_QKB   4096u        // 16*512 bf16 (16 KB)
#define WS_WV16  20480u       // 262144 bf16
#define WS_WO16  544768u
#define WS_W116  1069056u
#define WS_W216  1593344u     // 131072 bf16
#define WS_PH    2097152u     // [h][b][d] 8*4096*512 bf16 (32 MB)
#define WS_ZW    35651584u    // 4096*512 f32 (8 MB)
#define WS_CTX16 44040192u    // 4096*512 bf16 (4 MB)
#define WS_Z     48234496u    // 4096*512 f32 (8 MB)
#define WS_ZN16  56623104u    // 4 MB
#define WS_H116  60817408u    // 4 MB  -> total ~62 MB

extern "C" void kernel_launch(void* const* d_in, const int* in_sizes, int n_in,
                              void* d_out, int out_size, void* d_ws, size_t ws_size,
                              hipStream_t stream) {
    const float* H   = (const float*)d_in[0];
    const float* w   = (const float*)d_in[1];
    const float* aq  = (const float*)d_in[2];
    const float* ipw = (const float*)d_in[3];
    const float* ipb = (const float*)d_in[4];
    const float* opw = (const float*)d_in[5];
    const float* opb = (const float*)d_in[6];
    const float* lng = (const float*)d_in[7];
    const float* lnb = (const float*)d_in[8];
    const float* w1  = (const float*)d_in[9];
    const float* b1  = (const float*)d_in[10];
    const float* w2  = (const float*)d_in[11];
    const float* b2  = (const float*)d_in[12];
    float* out = (float*)d_out;
    char* ws = (char*)d_ws;

    float* qv            = (float*)(ws + WS_Q);
    unsigned short* qkb  = (unsigned short*)(ws + WS_QKB);
    unsigned short* Wv16 = (unsigned short*)(ws + WS_WV16);
    unsigned short* Wo16 = (unsigned short*)(ws + WS_WO16);
    unsigned short* w116 = (unsigned short*)(ws + WS_W116);
    unsigned short* w216 = (unsigned short*)(ws + WS_W216);
    unsigned short* ph   = (unsigned short*)(ws + WS_PH);
    float* zw            = (float*)(ws + WS_ZW);
    unsigned short* ctx16= (unsigned short*)(ws + WS_CTX16);
    float* z             = (float*)(ws + WS_Z);
    unsigned short* zn16 = (unsigned short*)(ws + WS_ZN16);
    unsigned short* h116 = (unsigned short*)(ws + WS_H116);

    // Weight conversions (Wv = in_proj_w rows 1024..1535), single launch
    k_conv_all<<<896, 256, 0, stream>>>(ipw + (size_t)1024 * 512, opw, w1, w2,
                                        Wv16, Wo16, w116, w216);

    // q, qkb precompute
    k_q<<<128, 256, 0, stream>>>(aq, ipw, ipb, qv);
    k_qk<<<16, 256, 0, stream>>>(qv, ipw, qkb);

    // Main streaming pass over H
    k_attn<<<4096, 256, 0, stream>>>(H, w, qkb, ph, zw);

    // Epilogue GEMM chain (bf16 MFMA)
    k_ctx  <<<dim3(8, 64), 256, 0, stream>>>(ph, Wv16, ipb, ctx16);
    k_zproj<<<dim3(8, 64), 256, 0, stream>>>(ctx16, Wo16, zw, opb, z);
    k_ln   <<<1024, 256, 0, stream>>>(z, lng, lnb, zn16);
    k_mlp1 <<<dim3(8, 64), 256, 0, stream>>>(zn16, w116, b1, h116);
    k_mlp2 <<<dim3(4, 64), 256, 0, stream>>>(h116, w216, b2, out);
}